// Round 4
// baseline (45.125 us; speedup 1.0000x reference)
//
#include <hip/hip_runtime.h>

// CNS residuals: vars (B=8, C=4, T=64, X=128, Y=128) f32
// out (B=8, 2, 62, 126, 126) f32: [mass, mom_x+mom_y] on inner region.
// R4: 2(x) x 4(y) outputs per thread. y-shifts via 8-float register windows
// (2 unaligned dwordx4 + shufflevector); x-neighbor rows shared across the
// two x-columns -> 42 loads / 8 outputs (was 56). Keeps XCD-chunked swizzle
// + nontemporal stores (keeps input L2/L3-resident).

typedef float vf4 __attribute__((ext_vector_type(4)));
typedef float vf4u __attribute__((ext_vector_type(4), aligned(4)));

__device__ __forceinline__ vf4 ld4(const float* __restrict__ p) {
    return *reinterpret_cast<const vf4u*>(p);
}

struct Win { vf4 lo, hi; };

// element e (=y offset within the 4-wide output) at y-shift s
#define SH(w, s) __builtin_shufflevector((w).lo, (w).hi, 2 + (s), 3 + (s), 4 + (s), 5 + (s))

__global__ __launch_bounds__(256) void cns_residuals_kernel(
    const float* __restrict__ vars,
    const float* __restrict__ s_dx, const float* __restrict__ s_dt,
    const float* __restrict__ s_eta, const float* __restrict__ s_zeta,
    float* __restrict__ out)
{
    const float dx = s_dx[0], dt = s_dt[0], eta = s_eta[0], zeta = s_zeta[0];
    const float bulk = zeta + eta * (1.0f / 3.0f);
    const float c1 = 2.0f * dx * dx;
    const float c2 = 2.0f * dt * dx;
    const float c3 = 4.0f * dt;
    const float c4 = 2.0f * dt;

    // bijective XCD-chunked swizzle, nwg = 3906 = 8*488 + 2
    const int i = blockIdx.x;
    const int xcd = i & 7;
    const int slot = i >> 3;
    const int lb = ((xcd < 2) ? xcd * 489 : 978 + (xcd - 2) * 488) + slot;

    const int tid = lb * 256 + threadIdx.x;
    const int j = tid & 31;            // y-group: outputs y = 1+4j .. 4+4j
    int r = tid >> 5;
    const int xh = r % 63; r /= 63;    // x-pair: rows x0, x0+1
    const int tp = r % 62;  const int b = r / 62;
    const int x0 = 1 + 2 * xh, t = tp + 1;
    const int yb = 1 + 4 * j;

    const size_t plane = 16384;                 // 128*128
    const size_t cstr  = (size_t)64 * plane;

    const float* base = vars + (size_t)b * 4 * cstr + (size_t)t * plane
                      + ((size_t)x0 << 7) + yb;
    const float* R0 = base;
    const float* U0 = base + cstr;
    const float* V0 = base + 2 * cstr;
    const float* P0 = base + 3 * cstr;

    const float mLo = (j == 0)  ? 0.0f : 1.0f;   // y' = -1 reads 0
    const float mHi = (j == 31) ? 0.0f : 1.0f;   // y' >= 128 reads 0

#define WIN(ptr) win_load(ptr, mLo, mHi)
    struct L {
        static __device__ __forceinline__ Win win_load(const float* p, float mLo, float mHi) {
            Win w; w.lo = ld4(p - 2); w.hi = ld4(p + 2);
            w.lo[0] *= mLo; w.hi[1] *= mHi; w.hi[2] *= mHi; w.hi[3] *= mHi;
            return w;
        }
    };
#undef WIN
#define WIN(ptr) L::win_load((ptr), mLo, mHi)

    // windows (8-float y-range, masked at y boundaries)
    const Win Rw0 = WIN(R0), Rw1 = WIN(R0 + 128);
    const Win Uwm = WIN(U0 - 128), Uw0 = WIN(U0), Uw1 = WIN(U0 + 128), Uw2 = WIN(U0 + 256);
    const Win Vwm = WIN(V0 - 128), Vw0 = WIN(V0), Vw1 = WIN(V0 + 128), Vw2 = WIN(V0 + 256);
    const Win Pw0 = WIN(P0), Pw1 = WIN(P0 + 128);

    // center-only 4-float loads (tail lanes' garbage elements are discarded)
    const vf4 zero = {0.0f, 0.0f, 0.0f, 0.0f};
    const vf4 Rc_m1 = ld4(R0 - 128), Rc_p2 = ld4(R0 + 256);
    const vf4 Pc_m1 = ld4(P0 - 128), Pc_p2 = ld4(P0 + 256);
    const vf4 Uc_m2 = (xh >= 1)  ? ld4(U0 - 256) : zero;  // row x0-2
    const vf4 Uc_p3 = (xh <= 61) ? ld4(U0 + 384) : zero;  // row x0+3
    const vf4 Rtp0 = ld4(R0 + plane), Rtp1 = ld4(R0 + plane + 128);
    const vf4 Rtm0 = ld4(R0 - plane), Rtm1 = ld4(R0 - plane + 128);
    const vf4 Utp0 = ld4(U0 + plane), Utp1 = ld4(U0 + plane + 128);
    const vf4 Utm0 = ld4(U0 - plane), Utm1 = ld4(U0 - plane + 128);
    const vf4 Vtp0 = ld4(V0 + plane), Vtp1 = ld4(V0 + plane + 128);
    const vf4 Vtm0 = ld4(V0 - plane), Vtm1 = ld4(V0 - plane + 128);

    // ---- column xc = 0 (x = x0) ----
    const vf4 rho0 = SH(Rw0, 0), u0c = SH(Uw0, 0), v0c = SH(Vw0, 0);
    const vf4 uxp0 = SH(Uw1, 0), uxm0 = SH(Uwm, 0);
    const vf4 vxp0 = SH(Vw1, 0), vxm0 = SH(Vwm, 0);
    const vf4 uyp0 = SH(Uw0, 1), uym0 = SH(Uw0, -1);
    const vf4 vyp0 = SH(Vw0, 1), vym0 = SH(Vw0, -1);
    const vf4 Dxu0 = uxp0 - uxm0, Dyu0 = uyp0 - uym0;
    const vf4 Dxv0 = vxp0 - vxm0, Dyv0 = vyp0 - vym0;
    const vf4 mass0 = (Rtp0 - Rtm0) * dx + rho0 * (Dxu0 + Dyv0) * dt
                    + u0c * (SH(Rw1, 0) - Rc_m1) * dt
                    + v0c * (SH(Rw0, 1) - SH(Rw0, -1)) * dt;
    const vf4 lapu0 = uxp0 + uxm0 + uyp0 + uym0 - 4.0f * u0c;
    const vf4 lapv0 = vxp0 + vxm0 + vyp0 + vym0 - 4.0f * v0c;
    const vf4 Dxdiv0 = SH(Uw2, 0) - 2.0f * u0c + Uc_m2
                     + SH(Vw1, 1) - SH(Vw1, -1) - SH(Vwm, 1) + SH(Vwm, -1);
    const vf4 Dydiv0 = SH(Vw0, 2) - 2.0f * v0c + SH(Vw0, -2)
                     + SH(Uw1, 1) - SH(Uwm, 1) - SH(Uw1, -1) + SH(Uwm, -1);
    const vf4 mom0 = rho0 * ((Utp0 - Utm0) + (Vtp0 - Vtm0)) * c1
                   + (u0c * (Dxu0 + Dxv0) + v0c * (Dyu0 + Dyv0)) * c2
                   + ((SH(Pw1, 0) - Pc_m1) + (SH(Pw0, 1) - SH(Pw0, -1))) * c2
                   - eta * (lapu0 + lapv0) * c3
                   - bulk * (Dxdiv0 + Dydiv0) * c4;

    // ---- column xc = 1 (x = x0+1) ----
    const vf4 rho1 = SH(Rw1, 0), u1c = SH(Uw1, 0), v1c = SH(Vw1, 0);
    const vf4 uxp1 = SH(Uw2, 0), uxm1 = SH(Uw0, 0);
    const vf4 vxp1 = SH(Vw2, 0), vxm1 = SH(Vw0, 0);
    const vf4 uyp1 = SH(Uw1, 1), uym1 = SH(Uw1, -1);
    const vf4 vyp1 = SH(Vw1, 1), vym1 = SH(Vw1, -1);
    const vf4 Dxu1 = uxp1 - uxm1, Dyu1 = uyp1 - uym1;
    const vf4 Dxv1 = vxp1 - vxm1, Dyv1 = vyp1 - vym1;
    const vf4 mass1 = (Rtp1 - Rtm1) * dx + rho1 * (Dxu1 + Dyv1) * dt
                    + u1c * (Rc_p2 - SH(Rw0, 0)) * dt
                    + v1c * (SH(Rw1, 1) - SH(Rw1, -1)) * dt;
    const vf4 lapu1 = uxp1 + uxm1 + uyp1 + uym1 - 4.0f * u1c;
    const vf4 lapv1 = vxp1 + vxm1 + vyp1 + vym1 - 4.0f * v1c;
    const vf4 Dxdiv1 = Uc_p3 - 2.0f * u1c + SH(Uwm, 0)
                     + SH(Vw2, 1) - SH(Vw2, -1) - SH(Vw0, 1) + SH(Vw0, -1);
    const vf4 Dydiv1 = SH(Vw1, 2) - 2.0f * v1c + SH(Vw1, -2)
                     + SH(Uw2, 1) - SH(Uw0, 1) - SH(Uw2, -1) + SH(Uw0, -1);
    const vf4 mom1 = rho1 * ((Utp1 - Utm1) + (Vtp1 - Vtm1)) * c1
                   + (u1c * (Dxu1 + Dxv1) + v1c * (Dyu1 + Dyv1)) * c2
                   + ((Pc_p2 - SH(Pw0, 0)) + (SH(Pw1, 1) - SH(Pw1, -1))) * c2
                   - eta * (lapu1 + lapv1) * c3
                   - bulk * (Dxdiv1 + Dydiv1) * c4;

    const size_t oplane = 126 * 126;
    const size_t ocstr  = (size_t)62 * oplane;
    float* o1 = out + (size_t)b * 2 * ocstr + (size_t)tp * oplane
              + (size_t)(2 * xh) * 126 + 4 * j;   // mass, row xp0
    float* o1b = o1 + 126;                         // mass, row xp1
    float* o2  = o1 + ocstr;                       // mom, row xp0
    float* o2b = o2 + 126;
    if (j < 31) {
        __builtin_nontemporal_store(mass0, reinterpret_cast<vf4u*>(o1));
        __builtin_nontemporal_store(mass1, reinterpret_cast<vf4u*>(o1b));
        __builtin_nontemporal_store(mom0,  reinterpret_cast<vf4u*>(o2));
        __builtin_nontemporal_store(mom1,  reinterpret_cast<vf4u*>(o2b));
    } else {  // outputs y=127,128 out of range; store only first 2
        __builtin_nontemporal_store(mass0[0], o1);      __builtin_nontemporal_store(mass0[1], o1 + 1);
        __builtin_nontemporal_store(mass1[0], o1b);     __builtin_nontemporal_store(mass1[1], o1b + 1);
        __builtin_nontemporal_store(mom0[0],  o2);      __builtin_nontemporal_store(mom0[1],  o2 + 1);
        __builtin_nontemporal_store(mom1[0],  o2b);     __builtin_nontemporal_store(mom1[1],  o2b + 1);
    }
}

extern "C" void kernel_launch(void* const* d_in, const int* in_sizes, int n_in,
                              void* d_out, int out_size, void* d_ws, size_t ws_size,
                              hipStream_t stream) {
    const float* vars   = (const float*)d_in[0];
    const float* s_dx   = (const float*)d_in[1];
    const float* s_dt   = (const float*)d_in[2];
    const float* s_eta  = (const float*)d_in[3];
    const float* s_zeta = (const float*)d_in[4];
    float* out = (float*)d_out;

    // threads = 8 * 62 * 63 * 32 = 999,936 = 3906 blocks * 256
    const int grid = 3906;
    hipLaunchKernelGGL(cns_residuals_kernel, dim3(grid), dim3(256), 0, stream,
                       vars, s_dx, s_dt, s_eta, s_zeta, out);
}

// Round 5
// 37.118 us; speedup vs baseline: 1.2157x; 1.2157x over previous
//
#include <hip/hip_runtime.h>

// CNS residuals: vars (B=8, C=4, T=64, X=128, Y=128) f32
// out (B=8, 2, 62, 126, 126) f32: [mass, mom_x+mom_y] on inner region.
// R5: back to R3's 1x4 mapping (2M threads, occupancy). Window loads are now
// ONE aligned dwordx4 per row (own chunk [4j..4j+3]) + 2-4 cross-lane
// __shfl edge elements (ds_bpermute, LDS pipe) instead of 2 misaligned ld4.
// L1 line-requests/wave: ~496 -> ~332. Keeps XCD swizzle + NT stores.

typedef float vf4 __attribute__((ext_vector_type(4)));
typedef float vf4u __attribute__((ext_vector_type(4), aligned(4)));

__device__ __forceinline__ vf4 ld4(const float* __restrict__ p) {
    return *reinterpret_cast<const vf4u*>(p);
}

struct Win { vf4 lo, hi; };
// logical window: lo = {y'=4j-1, 4j, 4j+1, 4j+2}, hi = {4j+3, 4j+4, 4j+5, 4j+6}
// output element e at shift s reads y' = 4j+1+e+s  ->  index 2+e+s
#define SH(w, s) __builtin_shufflevector((w).lo, (w).hi, 2 + (s), 3 + (s), 4 + (s), 5 + (s))

// standard window: shifts s in [-1,1] only -> need dn0 (4j+4), dn1 (4j+5)
__device__ __forceinline__ Win mkwin(vf4 c, float mHi) {
    const float dn0 = __shfl_down(c.x, 1) * mHi;
    const float dn1 = __shfl_down(c.y, 1) * mHi;
    Win w;
    w.lo = (vf4){0.0f, c.x, c.y, c.z};
    w.hi = (vf4){c.w, dn0, dn1, 0.0f};
    return w;
}

// full window: shifts s in [-2,2] -> also up3 (4j-1), dn2 (4j+6)
__device__ __forceinline__ Win mkwin2(vf4 c, float mLo, float mHi) {
    const float up3 = __shfl_up(c.w, 1) * mLo;
    const float dn0 = __shfl_down(c.x, 1) * mHi;
    const float dn1 = __shfl_down(c.y, 1) * mHi;
    const float dn2 = __shfl_down(c.z, 1) * mHi;
    Win w;
    w.lo = (vf4){up3, c.x, c.y, c.z};
    w.hi = (vf4){c.w, dn0, dn1, dn2};
    return w;
}

__global__ __launch_bounds__(256) void cns_residuals_kernel(
    const float* __restrict__ vars,
    const float* __restrict__ s_dx, const float* __restrict__ s_dt,
    const float* __restrict__ s_eta, const float* __restrict__ s_zeta,
    float* __restrict__ out)
{
    const float dx = s_dx[0], dt = s_dt[0], eta = s_eta[0], zeta = s_zeta[0];
    const float bulk = zeta + eta * (1.0f / 3.0f);
    const float c1 = 2.0f * dx * dx;
    const float c2 = 2.0f * dt * dx;
    const float c3 = 4.0f * dt;
    const float c4 = 2.0f * dt;

    // XCD-chunked bijective swizzle: nwg = 7812 = 8*976 + 4
    const int i = blockIdx.x;
    const int xcd = i & 7;
    const int slot = i >> 3;
    const int lb = ((xcd < 4) ? xcd * 977 : 3908 + (xcd - 4) * 976) + slot;

    const int tid = lb * 256 + threadIdx.x;
    const int j = tid & 31;            // y-group: outputs y = 4j+1 .. 4j+4
    int r = tid >> 5;
    const int xp = r % 126; r /= 126;
    const int tp = r % 62;  const int b = r / 62;
    const int x = xp + 1, t = tp + 1;
    const int yb = 1 + 4 * j;
    const int q = 4 * j;               // aligned chunk offset

    const size_t plane = 16384;                 // 128*128
    const size_t cstr  = (size_t)64 * plane;

    const float* baseA = vars + (size_t)b * 4 * cstr + (size_t)t * plane
                       + ((size_t)x << 7);
    const float* Rrow = baseA;
    const float* Urow = baseA + cstr;
    const float* Vrow = baseA + 2 * cstr;
    const float* Prow = baseA + 3 * cstr;

    const float mLo = (j == 0)  ? 0.0f : 1.0f;   // y' = -1 reads 0
    const float mHi = (j == 31) ? 0.0f : 1.0f;   // y' >= 128 reads 0

    // windows: 1 aligned ld4 + shuffles each
    const Win Rw0 = mkwin(ld4(Rrow + q), mHi);
    const Win Uwm = mkwin(ld4(Urow - 128 + q), mHi);
    const Win Uw0 = mkwin(ld4(Urow + q), mHi);
    const Win Uw1 = mkwin(ld4(Urow + 128 + q), mHi);
    const Win Vwm = mkwin(ld4(Vrow - 128 + q), mHi);
    const Win Vw0 = mkwin2(ld4(Vrow + q), mLo, mHi);
    const Win Vw1 = mkwin(ld4(Vrow + 128 + q), mHi);
    const Win Pw0 = mkwin(ld4(Prow + q), mHi);

    // center-only loads at yb (unaligned; tail garbage elements unused)
    const float* R0 = Rrow + yb;
    const float* U0 = Urow + yb;
    const float* V0 = Vrow + yb;
    const float* P0 = Prow + yb;
    const vf4 rxp = ld4(R0 + 128), rxm = ld4(R0 - 128);
    const vf4 rtp = ld4(R0 + plane), rtm = ld4(R0 - plane);
    const vf4 utp = ld4(U0 + plane), utm = ld4(U0 - plane);
    const vf4 vtp = ld4(V0 + plane), vtm = ld4(V0 - plane);
    const vf4 pxp = ld4(P0 + 128), pxm = ld4(P0 - 128);
    const vf4 zero = {0.0f, 0.0f, 0.0f, 0.0f};
    const vf4 uxp2 = (x <= 125) ? ld4(U0 + 256) : zero;
    const vf4 uxm2 = (x >= 2)   ? ld4(U0 - 256) : zero;

    const vf4 rho = SH(Rw0, 0);
    const vf4 u   = SH(Uw0, 0);
    const vf4 v   = SH(Vw0, 0);

    const vf4 uxp = SH(Uw1, 0), uxm = SH(Uwm, 0);
    const vf4 uyp = SH(Uw0, 1), uym = SH(Uw0, -1);
    const vf4 vxp = SH(Vw1, 0), vxm = SH(Vwm, 0);
    const vf4 vyp = SH(Vw0, 1), vym = SH(Vw0, -1);

    const vf4 Dt_rho = rtp - rtm;
    const vf4 Dx_rho = rxp - rxm;
    const vf4 Dy_rho = SH(Rw0, 1) - SH(Rw0, -1);
    const vf4 Dx_u = uxp - uxm, Dy_u = uyp - uym;
    const vf4 Dx_v = vxp - vxm, Dy_v = vyp - vym;

    const vf4 mass = Dt_rho * dx + rho * (Dx_u + Dy_v) * dt
                   + u * Dx_rho * dt + v * Dy_rho * dt;

    const vf4 Dt_u = utp - utm, Dt_v = vtp - vtm;
    const vf4 Dx_p = pxp - pxm;
    const vf4 Dy_p = SH(Pw0, 1) - SH(Pw0, -1);
    const vf4 lap_u = uxp + uxm + uyp + uym - 4.0f * u;
    const vf4 lap_v = vxp + vxm + vyp + vym - 4.0f * v;

    const vf4 Dx_div = uxp2 - 2.0f * u + uxm2
                     + SH(Vw1, 1) - SH(Vw1, -1)
                     - SH(Vwm, 1) + SH(Vwm, -1);
    const vf4 Dy_div = SH(Vw0, 2) - 2.0f * v + SH(Vw0, -2)
                     + SH(Uw1, 1) - SH(Uwm, 1)
                     - SH(Uw1, -1) + SH(Uwm, -1);

    const vf4 mom = rho * (Dt_u + Dt_v) * c1
                  + (u * (Dx_u + Dx_v) + v * (Dy_u + Dy_v)) * c2
                  + (Dx_p + Dy_p) * c2
                  - eta * (lap_u + lap_v) * c3
                  - bulk * (Dx_div + Dy_div) * c4;

    const size_t oplane = 126 * 126;
    const size_t ocstr  = (size_t)62 * oplane;
    float* o1 = out + (size_t)b * 2 * ocstr + (size_t)tp * oplane
              + (size_t)xp * 126 + 4 * j;
    float* o2 = o1 + ocstr;
    if (j < 31) {
        __builtin_nontemporal_store(mass, reinterpret_cast<vf4u*>(o1));
        __builtin_nontemporal_store(mom,  reinterpret_cast<vf4u*>(o2));
    } else {  // outputs y=127,128 out of range; store only 2
        __builtin_nontemporal_store(mass[0], o1);
        __builtin_nontemporal_store(mass[1], o1 + 1);
        __builtin_nontemporal_store(mom[0],  o2);
        __builtin_nontemporal_store(mom[1],  o2 + 1);
    }
}

extern "C" void kernel_launch(void* const* d_in, const int* in_sizes, int n_in,
                              void* d_out, int out_size, void* d_ws, size_t ws_size,
                              hipStream_t stream) {
    const float* vars   = (const float*)d_in[0];
    const float* s_dx   = (const float*)d_in[1];
    const float* s_dt   = (const float*)d_in[2];
    const float* s_eta  = (const float*)d_in[3];
    const float* s_zeta = (const float*)d_in[4];
    float* out = (float*)d_out;

    const int grid = 7812;  // 8*62*126*32 threads / 256
    hipLaunchKernelGGL(cns_residuals_kernel, dim3(grid), dim3(256), 0, stream,
                       vars, s_dx, s_dt, s_eta, s_zeta, out);
}